// Round 1
// baseline (193.819 us; speedup 1.0000x reference)
//
#include <hip/hip_runtime.h>
#include <stdint.h>

// ---------- types ----------
typedef unsigned short bf16u;                                    // raw bf16 bits
typedef __attribute__((ext_vector_type(8))) short s16x8;         // MFMA A/B frag (8 bf16)
typedef __attribute__((ext_vector_type(4))) float f32x4;         // MFMA C/D frag

static __device__ __forceinline__ bf16u f2bf(float f) {
    uint32_t u = __float_as_uint(f);
    uint32_t r = (u + 0x7FFFu + ((u >> 16) & 1u)) >> 16;         // RNE
    return (bf16u)r;
}

static __device__ __forceinline__ f32x4 mfma16(s16x8 a, s16x8 b, f32x4 c) {
    return __builtin_amdgcn_mfma_f32_16x16x32_bf16(a, b, c, 0, 0, 0);
}

#define GLDS(gsrc, ldst)                                                        \
    __builtin_amdgcn_global_load_lds(                                           \
        (const __attribute__((address_space(1))) void*)(gsrc),                  \
        (__attribute__((address_space(3))) void*)(ldst), 16, 0, 0)

// ---------- fp32 -> bf16 convert ----------
__global__ __launch_bounds__(256) void cvt_f32_bf16_kernel(
    const float* __restrict__ in, bf16u* __restrict__ out, int n) {
    union Pack { bf16u h[8]; uint4 u; };
    for (int i = (blockIdx.x * 256 + threadIdx.x) * 8; i < n; i += gridDim.x * 256 * 8) {
        const float4 a = *(const float4*)(in + i);
        const float4 b = *(const float4*)(in + i + 4);
        Pack p;
        p.h[0] = f2bf(a.x); p.h[1] = f2bf(a.y); p.h[2] = f2bf(a.z); p.h[3] = f2bf(a.w);
        p.h[4] = f2bf(b.x); p.h[5] = f2bf(b.y); p.h[6] = f2bf(b.z); p.h[7] = f2bf(b.w);
        *(uint4*)(out + i) = p.u;
    }
}

// ---------- GEMM: C = A @ Bt^T (+bias). A:[M,K] bf16, Bt:[N,K] bf16 ----------
// MODE 0: fp32 out to Cf[M,N].  MODE 1: scatter bf16 into Q/K/V [BH][2048][64].
template <int MODE>
__global__ __launch_bounds__(256) void gemm_bt_kernel(
    const bf16u* __restrict__ A, const bf16u* __restrict__ Bt,
    const float* __restrict__ bias, float* __restrict__ Cf,
    bf16u* __restrict__ Qo, bf16u* __restrict__ Ko, bf16u* __restrict__ Vo,
    int M, int N, int K) {
    __shared__ bf16u As[128 * 32];   // [row][k], 64B rows, linear (global_load_lds dest)
    __shared__ bf16u Bs[128 * 32];
    const int tid  = threadIdx.x;
    const int wave = tid >> 6, lane = tid & 63;
    const int wr = wave >> 1, wc = wave & 1;
    const int ri = lane & 15, hi = lane >> 4;
    const int m0 = blockIdx.x * 128, n0 = blockIdx.y * 128;

    f32x4 acc[4][4];
#pragma unroll
    for (int i = 0; i < 4; ++i)
#pragma unroll
        for (int j = 0; j < 4; ++j) acc[i][j] = (f32x4){0.f, 0.f, 0.f, 0.f};

    for (int k0 = 0; k0 < K; k0 += 32) {
        __syncthreads();  // previous iteration's reads done before overwrite
#pragma unroll
        for (int it = 0; it < 2; ++it) {
            const int chunk = it * 4 + wave;          // 0..7, wave-uniform
            const int e = chunk * 512 + lane * 8;     // bf16 element index in tile
            const int r = e >> 5, c = e & 31;
            GLDS(A  + (size_t)(m0 + r) * K + (k0 + c), As + chunk * 512);
            GLDS(Bt + (size_t)(n0 + r) * K + (k0 + c), Bs + chunk * 512);
        }
        __syncthreads();  // drains vmcnt -> staged data visible
        s16x8 af[4], bfr[4];
#pragma unroll
        for (int i = 0; i < 4; ++i) {
            af[i]  = *(const s16x8*)(As + (wr * 64 + i * 16 + ri) * 32 + hi * 8);
            bfr[i] = *(const s16x8*)(Bs + (wc * 64 + i * 16 + ri) * 32 + hi * 8);
        }
#pragma unroll
        for (int i = 0; i < 4; ++i)
#pragma unroll
            for (int j = 0; j < 4; ++j) acc[i][j] = mfma16(af[i], bfr[j], acc[i][j]);
    }

    // epilogue: D layout row=(lane>>4)*4+r, col=lane&15
#pragma unroll
    for (int i = 0; i < 4; ++i) {
#pragma unroll
        for (int j = 0; j < 4; ++j) {
#pragma unroll
            for (int r = 0; r < 4; ++r) {
                const int row = m0 + wr * 64 + i * 16 + hi * 4 + r;
                const int col = n0 + wc * 64 + j * 16 + ri;
                const float v = acc[i][j][r] + bias[col];
                if constexpr (MODE == 0) {
                    Cf[(size_t)row * N + col] = v;
                } else {
                    const int which = col >> 10, h = (col >> 6) & 15, d = col & 63;
                    const int b = row >> 11, t = row & 2047;
                    bf16u* dst = (which == 0) ? Qo : (which == 1) ? Ko : Vo;
                    dst[(((size_t)(b * 16 + h)) * 2048 + t) * 64 + d] = f2bf(v);
                }
            }
        }
    }
}

// ---------- V transpose: [BH][2048][64] -> [BH][64][2048] ----------
__global__ __launch_bounds__(256) void transpose_v_kernel(
    const bf16u* __restrict__ Vin, bf16u* __restrict__ Vt) {
    __shared__ bf16u Tl[64 * 80];  // [t][d], pad to 80 (160B rows, 16B-aligned)
    const int tid = threadIdx.x;
    const int bh = blockIdx.y;
    const int t0 = blockIdx.x * 64;
    const bf16u* src = Vin + ((size_t)bh * 2048 + t0) * 64;
#pragma unroll
    for (int it = 0; it < 2; ++it) {
        const int chunk = it * 256 + tid;  // 0..511
        const int r = chunk >> 3, c8 = chunk & 7;
        *(s16x8*)(Tl + r * 80 + c8 * 8) = *(const s16x8*)(src + chunk * 8);
    }
    __syncthreads();
    bf16u* dst = Vt + (size_t)bh * 64 * 2048 + t0;
#pragma unroll
    for (int it = 0; it < 2; ++it) {
        const int chunk = it * 256 + tid;
        const int d = chunk >> 3, tc8 = chunk & 7;
        union { bf16u h[8]; uint4 u; } p;
#pragma unroll
        for (int j = 0; j < 8; ++j) p.h[j] = Tl[(tc8 * 8 + j) * 80 + d];
        *(uint4*)(dst + (size_t)d * 2048 + tc8 * 8) = p.u;
    }
}

// ---------- flash attention: Q,K [BH][2048][64], Vt [BH][64][2048] ----------
// grid (T/64, BH); 4 waves x 16 q-rows; KV tile 64; scale=1/8
__global__ __launch_bounds__(256) void attn_kernel(
    const bf16u* __restrict__ Q, const bf16u* __restrict__ K,
    const bf16u* __restrict__ Vt, bf16u* __restrict__ O) {
    __shared__ bf16u Ks[64 * 80];      // [kv][d], pad 80
    __shared__ bf16u Vs[64 * 80];      // [d][kv], pad 80
    __shared__ bf16u Ps[4][16 * 80];   // per-wave P tile [q][kv]
    const int tid = threadIdx.x, wave = tid >> 6, lane = tid & 63;
    const int ri = lane & 15, hi = lane >> 4;
    const int bh = blockIdx.y, b = bh >> 4, h = bh & 15;
    const int q0 = blockIdx.x * 64 + wave * 16;  // local token base of this wave
    const bf16u* Qb = Q  + (size_t)bh * 2048 * 64;
    const bf16u* Kb = K  + (size_t)bh * 2048 * 64;
    const bf16u* Vb = Vt + (size_t)bh * 64 * 2048;

    s16x8 qf[2];
#pragma unroll
    for (int c = 0; c < 2; ++c)
        qf[c] = *(const s16x8*)(Qb + (size_t)(q0 + ri) * 64 + c * 32 + hi * 8);

    f32x4 o[4];
    float m[4], l[4];
#pragma unroll
    for (int r = 0; r < 4; ++r) { m[r] = -1e30f; l[r] = 0.f; }
#pragma unroll
    for (int nt = 0; nt < 4; ++nt) o[nt] = (f32x4){0.f, 0.f, 0.f, 0.f};

    for (int kt = 0; kt < 32; ++kt) {
        __syncthreads();  // previous tile fully consumed
#pragma unroll
        for (int it = 0; it < 2; ++it) {
            const int chunk = it * 256 + tid;
            const int r = chunk >> 3, c8 = chunk & 7;
            *(s16x8*)(Ks + r * 80 + c8 * 8) =
                *(const s16x8*)(Kb + (size_t)kt * 4096 + chunk * 8);
            *(s16x8*)(Vs + r * 80 + c8 * 8) =
                *(const s16x8*)(Vb + (size_t)r * 2048 + kt * 64 + c8 * 8);
        }
        __syncthreads();

        // S = Q K^T (16 x 64)
        f32x4 s[4];
#pragma unroll
        for (int nt = 0; nt < 4; ++nt) {
            s[nt] = (f32x4){0.f, 0.f, 0.f, 0.f};
#pragma unroll
            for (int c = 0; c < 2; ++c) {
                s16x8 kf = *(const s16x8*)(Ks + (nt * 16 + ri) * 80 + c * 32 + hi * 8);
                s[nt] = mfma16(qf[c], kf, s[nt]);
            }
        }
#pragma unroll
        for (int nt = 0; nt < 4; ++nt)
#pragma unroll
            for (int r = 0; r < 4; ++r) s[nt][r] *= 0.125f;

        // online softmax (rows = hi*4+r, cols across 16 lanes + 4 tiles)
        float pm[4];
#pragma unroll
        for (int r = 0; r < 4; ++r)
            pm[r] = fmaxf(fmaxf(s[0][r], s[1][r]), fmaxf(s[2][r], s[3][r]));
#pragma unroll
        for (int off = 1; off < 16; off <<= 1)
#pragma unroll
            for (int r = 0; r < 4; ++r) pm[r] = fmaxf(pm[r], __shfl_xor(pm[r], off));

        float al[4], rs[4];
#pragma unroll
        for (int r = 0; r < 4; ++r) {
            const float mn = fmaxf(m[r], pm[r]);
            al[r] = __expf(m[r] - mn);
            m[r] = mn;
            rs[r] = 0.f;
        }
#pragma unroll
        for (int nt = 0; nt < 4; ++nt)
#pragma unroll
            for (int r = 0; r < 4; ++r) {
                const float p = __expf(s[nt][r] - m[r]);
                s[nt][r] = p;
                rs[r] += p;
            }
#pragma unroll
        for (int off = 1; off < 16; off <<= 1)
#pragma unroll
            for (int r = 0; r < 4; ++r) rs[r] += __shfl_xor(rs[r], off);
#pragma unroll
        for (int r = 0; r < 4; ++r) l[r] = l[r] * al[r] + rs[r];
#pragma unroll
        for (int nt = 0; nt < 4; ++nt)
#pragma unroll
            for (int r = 0; r < 4; ++r) o[nt][r] *= al[r];

        // restage P (D-layout -> A-fragment layout) through LDS
#pragma unroll
        for (int nt = 0; nt < 4; ++nt)
#pragma unroll
            for (int r = 0; r < 4; ++r)
                Ps[wave][(hi * 4 + r) * 80 + nt * 16 + ri] = f2bf(s[nt][r]);
        __syncthreads();

        // O += P @ V  (Vs rows are V^T: [d][kv])
#pragma unroll
        for (int kc = 0; kc < 2; ++kc) {
            s16x8 pf = *(const s16x8*)(&Ps[wave][ri * 80 + kc * 32 + hi * 8]);
#pragma unroll
            for (int nt = 0; nt < 4; ++nt) {
                s16x8 vf = *(const s16x8*)(Vs + (nt * 16 + ri) * 80 + kc * 32 + hi * 8);
                o[nt] = mfma16(pf, vf, o[nt]);
            }
        }
    }

    // epilogue: write [B*T][1024] bf16 (token-major for out-proj GEMM)
#pragma unroll
    for (int r = 0; r < 4; ++r) {
        const float inv = 1.f / l[r];
        const int t = q0 + hi * 4 + r;
#pragma unroll
        for (int nt = 0; nt < 4; ++nt)
            O[((size_t)b * 2048 + t) * 1024 + h * 64 + nt * 16 + ri] =
                f2bf(o[nt][r] * inv);
    }
}

// ---------- launch ----------
extern "C" void kernel_launch(void* const* d_in, const int* in_sizes, int n_in,
                              void* d_out, int out_size, void* d_ws, size_t ws_size,
                              hipStream_t stream) {
    const float* x     = (const float*)d_in[0];
    const float* w_in  = (const float*)d_in[1];
    const float* b_in  = (const float*)d_in[2];
    const float* w_out = (const float*)d_in[3];
    const float* b_out = (const float*)d_in[4];
    float* out = (float*)d_out;

    char* ws = (char*)d_ws;
    bf16u* xb    = (bf16u*)(ws);                          // 8 MB  (reused as attnb)
    bf16u* wqkvb = (bf16u*)(ws + 8388608);                // 6 MB
    bf16u* woutb = (bf16u*)(ws + 14680064);               // 2 MB
    bf16u* qb    = (bf16u*)(ws + 16777216);               // 8 MB
    bf16u* kb    = (bf16u*)(ws + 25165824);               // 8 MB
    bf16u* vb    = (bf16u*)(ws + 33554432);               // 8 MB
    bf16u* vtb   = (bf16u*)(ws + 41943040);               // 8 MB  (total 48 MB)
    bf16u* attnb = xb;  // x is dead after the QKV GEMM

    cvt_f32_bf16_kernel<<<2048, 256, 0, stream>>>(x, xb, 4096 * 1024);
    cvt_f32_bf16_kernel<<<1536, 256, 0, stream>>>(w_in, wqkvb, 3072 * 1024);
    cvt_f32_bf16_kernel<<<512, 256, 0, stream>>>(w_out, woutb, 1024 * 1024);

    gemm_bt_kernel<1><<<dim3(32, 24), 256, 0, stream>>>(
        xb, wqkvb, b_in, nullptr, qb, kb, vb, 4096, 3072, 1024);

    transpose_v_kernel<<<dim3(32, 32), 256, 0, stream>>>(vb, vtb);

    attn_kernel<<<dim3(32, 32), 256, 0, stream>>>(qb, kb, vtb, attnb);

    gemm_bt_kernel<0><<<dim3(32, 8), 256, 0, stream>>>(
        attnb, woutb, b_out, out, nullptr, nullptr, nullptr, 4096, 1024, 1024);
}

// Round 3
// 185.730 us; speedup vs baseline: 1.0436x; 1.0436x over previous
//
#include <hip/hip_runtime.h>
#include <stdint.h>

// ---------- types ----------
typedef unsigned short bf16u;                                    // raw bf16 bits
typedef unsigned int u32;
typedef __attribute__((ext_vector_type(8))) short s16x8;         // MFMA A/B frag (8 bf16)
typedef __attribute__((ext_vector_type(4))) float f32x4;         // 16x16 C/D frag
typedef __attribute__((ext_vector_type(16))) float f32x16;       // 32x32 C/D frag

static __device__ __forceinline__ bf16u f2bf(float f) {
    uint32_t u = __float_as_uint(f);
    uint32_t r = (u + 0x7FFFu + ((u >> 16) & 1u)) >> 16;         // RNE
    return (bf16u)r;
}
static __device__ __forceinline__ u32 pack2(float lo, float hi) {
    return (u32)f2bf(lo) | ((u32)f2bf(hi) << 16);
}

static __device__ __forceinline__ f32x4 mfma16(s16x8 a, s16x8 b, f32x4 c) {
    return __builtin_amdgcn_mfma_f32_16x16x32_bf16(a, b, c, 0, 0, 0);
}
static __device__ __forceinline__ f32x16 mfma32(s16x8 a, s16x8 b, f32x16 c) {
    return __builtin_amdgcn_mfma_f32_32x32x16_bf16(a, b, c, 0, 0, 0);
}

#define GLDS(gsrc, ldst)                                                        \
    __builtin_amdgcn_global_load_lds(                                           \
        (const __attribute__((address_space(1))) void*)(gsrc),                  \
        (__attribute__((address_space(3))) void*)(ldst), 16, 0, 0)

// ---------- fp32 -> bf16 convert ----------
__global__ __launch_bounds__(256) void cvt_f32_bf16_kernel(
    const float* __restrict__ in, bf16u* __restrict__ out, int n) {
    union Pack { bf16u h[8]; uint4 u; };
    for (int i = (blockIdx.x * 256 + threadIdx.x) * 8; i < n; i += gridDim.x * 256 * 8) {
        const float4 a = *(const float4*)(in + i);
        const float4 b = *(const float4*)(in + i + 4);
        Pack p;
        p.h[0] = f2bf(a.x); p.h[1] = f2bf(a.y); p.h[2] = f2bf(a.z); p.h[3] = f2bf(a.w);
        p.h[4] = f2bf(b.x); p.h[5] = f2bf(b.y); p.h[6] = f2bf(b.z); p.h[7] = f2bf(b.w);
        *(uint4*)(out + i) = p.u;
    }
}

// ---------- GEMM: C = A @ Bt^T (+bias). A:[M,K] bf16, Bt:[N,K] bf16 ----------
// MODE 0: fp32 out to Cf[M,N].
// MODE 1: scatter bf16: Q,K -> [BH][2048][64]; V -> TRANSPOSED [BH][64][2048].
template <int MODE>
__global__ __launch_bounds__(256) void gemm_bt_kernel(
    const bf16u* __restrict__ A, const bf16u* __restrict__ Bt,
    const float* __restrict__ bias, float* __restrict__ Cf,
    bf16u* __restrict__ Qo, bf16u* __restrict__ Ko, bf16u* __restrict__ Vto,
    int M, int N, int K) {
    __shared__ bf16u As[128 * 32];   // [row][k], linear (global_load_lds dest)
    __shared__ bf16u Bs[128 * 32];
    const int tid  = threadIdx.x;
    const int wave = tid >> 6, lane = tid & 63;
    const int wr = wave >> 1, wc = wave & 1;
    const int ri = lane & 15, hi = lane >> 4;
    const int m0 = blockIdx.x * 128, n0 = blockIdx.y * 128;

    f32x4 acc[4][4];
#pragma unroll
    for (int i = 0; i < 4; ++i)
#pragma unroll
        for (int j = 0; j < 4; ++j) acc[i][j] = (f32x4){0.f, 0.f, 0.f, 0.f};

    for (int k0 = 0; k0 < K; k0 += 32) {
        __syncthreads();
#pragma unroll
        for (int it = 0; it < 2; ++it) {
            const int chunk = it * 4 + wave;          // 0..7, wave-uniform
            const int e = chunk * 512 + lane * 8;
            const int r = e >> 5, c = e & 31;
            GLDS(A  + (size_t)(m0 + r) * K + (k0 + c), As + chunk * 512);
            GLDS(Bt + (size_t)(n0 + r) * K + (k0 + c), Bs + chunk * 512);
        }
        __syncthreads();
        s16x8 af[4], bfr[4];
#pragma unroll
        for (int i = 0; i < 4; ++i) {
            af[i]  = *(const s16x8*)(As + (wr * 64 + i * 16 + ri) * 32 + hi * 8);
            bfr[i] = *(const s16x8*)(Bs + (wc * 64 + i * 16 + ri) * 32 + hi * 8);
        }
#pragma unroll
        for (int i = 0; i < 4; ++i)
#pragma unroll
            for (int j = 0; j < 4; ++j) acc[i][j] = mfma16(af[i], bfr[j], acc[i][j]);
    }

    // epilogue: D layout row=(lane>>4)*4+r, col=lane&15
#pragma unroll
    for (int i = 0; i < 4; ++i) {
#pragma unroll
        for (int j = 0; j < 4; ++j) {
#pragma unroll
            for (int r = 0; r < 4; ++r) {
                const int row = m0 + wr * 64 + i * 16 + hi * 4 + r;
                const int col = n0 + wc * 64 + j * 16 + ri;
                const float v = acc[i][j][r] + bias[col];
                if constexpr (MODE == 0) {
                    Cf[(size_t)row * N + col] = v;
                } else {
                    const int which = col >> 10, h = (col >> 6) & 15, d = col & 63;
                    const int b = row >> 11, t = row & 2047;
                    const int bh = b * 16 + h;
                    if (which == 2) {
                        Vto[(((size_t)bh) * 64 + d) * 2048 + t] = f2bf(v);
                    } else {
                        bf16u* dst = (which == 0) ? Qo : Ko;
                        dst[(((size_t)bh) * 2048 + t) * 64 + d] = f2bf(v);
                    }
                }
            }
        }
    }
}

// ---------- flash attention (swapped QK^T, 32x32 MFMA) ----------
// Q,K: [BH][2048][64]; Vt: [BH][64][2048]; O: [B][2048][1024] bf16
// Block: 4 waves x 32 q-rows = 128 q. KV tile = 64. Grid (2048/128, BH).
// LDS rows padded to 72 elems (144B): bank-quad = (row+slot)&7 -> conflict-free
// at the 8-hits/bank floor for both the b128 staging writes and MFMA reads.
__global__ __launch_bounds__(256) void attn_kernel(
    const bf16u* __restrict__ Q, const bf16u* __restrict__ K,
    const bf16u* __restrict__ Vt, bf16u* __restrict__ O) {
    __shared__ bf16u Ks[64 * 72];    // [k][d] pad72
    __shared__ bf16u Vs[64 * 72];    // [d][k] pad72
    const int tid = threadIdx.x, lane = tid & 63;
    const int wave = tid >> 6;
    const int ri = lane & 31, hi = lane >> 5;          // q-col / lane-half
    const int bh = blockIdx.y, b = bh >> 4, h = bh & 15;
    const int q0 = blockIdx.x * 128 + wave * 32;
    const bf16u* Qb = Q  + (size_t)bh * 2048 * 64;
    const bf16u* Kb = K  + (size_t)bh * 2048 * 64;
    const bf16u* Vb = Vt + (size_t)bh * 64 * 2048;

    // Q fragment (B-operand): lane holds row q0+ri, d = 16c + 8hi + e
    s16x8 qf[4];
#pragma unroll
    for (int c = 0; c < 4; ++c)
        qf[c] = *(const s16x8*)(Qb + (size_t)(q0 + ri) * 64 + c * 16 + hi * 8);

    f32x16 oacc[2];
#pragma unroll
    for (int r = 0; r < 16; ++r) { oacc[0][r] = 0.f; oacc[1][r] = 0.f; }
    float m = -1e30f, lsum = 0.f;

    for (int kt = 0; kt < 32; ++kt) {
        const int kv0 = kt * 64;
        // load tile to registers (issued before the barrier -> overlaps drain)
        uint4 kreg[2], vreg[2];
#pragma unroll
        for (int p = 0; p < 2; ++p) {
            const int chunkid = p * 256 + tid;       // 0..511
            const int row = chunkid >> 3, c = chunkid & 7;
            kreg[p] = *(const uint4*)(Kb + (size_t)(kv0 + row) * 64 + c * 8);
            vreg[p] = *(const uint4*)(Vb + (size_t)row * 2048 + kv0 + c * 8);
        }
        __syncthreads();  // previous tile's LDS reads complete
#pragma unroll
        for (int p = 0; p < 2; ++p) {
            const int chunkid = p * 256 + tid;
            const int row = chunkid >> 3, c = chunkid & 7;
            *(uint4*)(Ks + row * 72 + c * 8) = kreg[p];
            *(uint4*)(Vs + row * 72 + c * 8) = vreg[p];
        }
        __syncthreads();

        // S^T[k][q] = sum_d K[k][d] Q[q][d]  (2 tiles of 32k x 32q, 4 mfma each)
        f32x16 sa[2];
#pragma unroll
        for (int r = 0; r < 16; ++r) { sa[0][r] = 0.f; sa[1][r] = 0.f; }
#pragma unroll
        for (int kb2 = 0; kb2 < 2; ++kb2) {
            const int row = kb2 * 32 + ri;
#pragma unroll
            for (int c = 0; c < 4; ++c) {
                s16x8 kf = *(const s16x8*)(Ks + row * 72 + (2 * c + hi) * 8);
                sa[kb2] = mfma32(kf, qf[c], sa[kb2]);
            }
        }

        // ---- online softmax, fully in-register (lane owns q = q0+ri) ----
        // lane holds k = 32*kb2 + (r&3) + 8*(r>>2) + 4*hi; partner lane^32 has rest
        float pmt[16];
#pragma unroll
        for (int r = 0; r < 16; ++r) pmt[r] = fmaxf(sa[0][r], sa[1][r]);
#pragma unroll
        for (int s = 8; s > 0; s >>= 1)
#pragma unroll
            for (int r = 0; r < s; ++r) pmt[r] = fmaxf(pmt[r], pmt[r + s]);
        float pm = fmaxf(pmt[0], __shfl_xor(pmt[0], 32));
        const float mn = fmaxf(m, pm);
        const float al = __expf((m - mn) * 0.125f);
        m = mn;
        float rs0 = 0.f, rs1 = 0.f, rs2 = 0.f, rs3 = 0.f;
#pragma unroll
        for (int kb2 = 0; kb2 < 2; ++kb2)
#pragma unroll
            for (int r = 0; r < 16; ++r) {
                const float p = __expf((sa[kb2][r] - mn) * 0.125f);
                sa[kb2][r] = p;
                if ((r & 3) == 0) rs0 += p;
                else if ((r & 3) == 1) rs1 += p;
                else if ((r & 3) == 2) rs2 += p;
                else rs3 += p;
            }
        float rs = (rs0 + rs1) + (rs2 + rs3);
        rs += __shfl_xor(rs, 32);
        lsum = lsum * al + rs;
#pragma unroll
        for (int r = 0; r < 16; ++r) { oacc[0][r] *= al; oacc[1][r] *= al; }

        // ---- pack P^T into B-operand frags: pb[k4] holds k = 16*k4 + 8*hi + e ----
        s16x8 pb[4];
#pragma unroll
        for (int blk = 0; blk < 2; ++blk) {
            u32 pk[4][2];
#pragma unroll
            for (int j = 0; j < 4; ++j) {
                pk[j][0] = pack2(sa[blk][4 * j + 0], sa[blk][4 * j + 1]);
                pk[j][1] = pack2(sa[blk][4 * j + 2], sa[blk][4 * j + 3]);
            }
#pragma unroll
            for (int half = 0; half < 2; ++half) {
                const int ja = 2 * half, jb = ja + 1;
                // keep own-parity quad, exchange the other with lane^32
                u32 keep0 = hi ? pk[jb][0] : pk[ja][0];
                u32 keep1 = hi ? pk[jb][1] : pk[ja][1];
                u32 send0 = hi ? pk[ja][0] : pk[jb][0];
                u32 send1 = hi ? pk[ja][1] : pk[jb][1];
                u32 recv0 = __shfl_xor(send0, 32);
                u32 recv1 = __shfl_xor(send1, 32);
                union { u32 w[4]; s16x8 v; } pu;
                pu.w[0] = hi ? recv0 : keep0;   // e0,e1
                pu.w[1] = hi ? recv1 : keep1;   // e2,e3
                pu.w[2] = hi ? keep0 : recv0;   // e4,e5
                pu.w[3] = hi ? keep1 : recv1;   // e6,e7
                pb[blk * 2 + half] = pu.v;
            }
        }

        // ---- O^T[d][q] += sum_k V^T[d][k] P^T[k][q] ----
#pragma unroll
        for (int dt = 0; dt < 2; ++dt) {
            const int row = dt * 32 + ri;
#pragma unroll
            for (int k4 = 0; k4 < 4; ++k4) {
                s16x8 vf = *(const s16x8*)(Vs + row * 72 + (2 * k4 + hi) * 8);
                oacc[dt] = mfma32(vf, pb[k4], oacc[dt]);
            }
        }
    }

    // epilogue: lane owns q-column; d = (r&3) + 8*(r>>2) + 4*hi + 32*dt
    const float inv = 1.f / lsum;
    const int t = q0 + ri;
    bf16u* Ob = O + ((size_t)b * 2048 + t) * 1024 + h * 64;
#pragma unroll
    for (int dt = 0; dt < 2; ++dt)
#pragma unroll
        for (int j = 0; j < 4; ++j) {
            const int d0 = dt * 32 + j * 8 + hi * 4;
            u32 w0 = pack2(oacc[dt][4 * j + 0] * inv, oacc[dt][4 * j + 1] * inv);
            u32 w1 = pack2(oacc[dt][4 * j + 2] * inv, oacc[dt][4 * j + 3] * inv);
            uint2 wv; wv.x = w0; wv.y = w1;
            *(uint2*)(Ob + d0) = wv;
        }
}

// ---------- launch ----------
extern "C" void kernel_launch(void* const* d_in, const int* in_sizes, int n_in,
                              void* d_out, int out_size, void* d_ws, size_t ws_size,
                              hipStream_t stream) {
    const float* x     = (const float*)d_in[0];
    const float* w_in  = (const float*)d_in[1];
    const float* b_in  = (const float*)d_in[2];
    const float* w_out = (const float*)d_in[3];
    const float* b_out = (const float*)d_in[4];
    float* out = (float*)d_out;

    char* ws = (char*)d_ws;
    bf16u* xb    = (bf16u*)(ws);                          // 8 MB  (reused as attnb)
    bf16u* wqkvb = (bf16u*)(ws + 8388608);                // 6 MB
    bf16u* woutb = (bf16u*)(ws + 14680064);               // 2 MB
    bf16u* qb    = (bf16u*)(ws + 16777216);               // 8 MB
    bf16u* kb    = (bf16u*)(ws + 25165824);               // 8 MB
    bf16u* vtb   = (bf16u*)(ws + 33554432);               // 8 MB (V stored transposed)
    bf16u* attnb = xb;  // x is dead after the QKV GEMM

    cvt_f32_bf16_kernel<<<2048, 256, 0, stream>>>(x, xb, 4096 * 1024);
    cvt_f32_bf16_kernel<<<1536, 256, 0, stream>>>(w_in, wqkvb, 3072 * 1024);
    cvt_f32_bf16_kernel<<<512, 256, 0, stream>>>(w_out, woutb, 1024 * 1024);

    gemm_bt_kernel<1><<<dim3(32, 24), 256, 0, stream>>>(
        xb, wqkvb, b_in, nullptr, qb, kb, vtb, 4096, 3072, 1024);

    attn_kernel<<<dim3(16, 32), 256, 0, stream>>>(qb, kb, vtb, attnb);

    gemm_bt_kernel<0><<<dim3(32, 8), 256, 0, stream>>>(
        attnb, woutb, b_out, out, nullptr, nullptr, nullptr, 4096, 1024, 1024);
}

// Round 5
// 174.652 us; speedup vs baseline: 1.1097x; 1.0634x over previous
//
#include <hip/hip_runtime.h>
#include <stdint.h>

// ---------- types ----------
typedef unsigned short bf16u;                                    // raw bf16 bits
typedef unsigned int u32;
typedef __attribute__((ext_vector_type(8))) short s16x8;         // MFMA A/B frag (8 bf16)
typedef __attribute__((ext_vector_type(4))) float f32x4;         // 16x16 C/D frag
typedef __attribute__((ext_vector_type(16))) float f32x16;       // 32x32 C/D frag

// Q is pre-scaled by 1/sqrt(64) * log2(e) so softmax runs in exp2 domain.
#define QSCALE 0.18033688011112042f

static __device__ __forceinline__ bf16u f2bf(float f) {
    uint32_t u = __float_as_uint(f);
    uint32_t r = (u + 0x7FFFu + ((u >> 16) & 1u)) >> 16;         // RNE
    return (bf16u)r;
}
static __device__ __forceinline__ u32 pack2(float lo, float hi) {
    return (u32)f2bf(lo) | ((u32)f2bf(hi) << 16);
}
// D.lo = bf16(S0), D.hi = bf16(S1), RNE (T12 recipe, m240)
static __device__ __forceinline__ u32 cvtpk(float lo, float hi) {
    u32 r;
    asm("v_cvt_pk_bf16_f32 %0, %1, %2" : "=v"(r) : "v"(lo), "v"(hi));
    return r;
}

static __device__ __forceinline__ f32x4 mfma16(s16x8 a, s16x8 b, f32x4 c) {
    return __builtin_amdgcn_mfma_f32_16x16x32_bf16(a, b, c, 0, 0, 0);
}
static __device__ __forceinline__ f32x16 mfma32(s16x8 a, s16x8 b, f32x16 c) {
    return __builtin_amdgcn_mfma_f32_32x32x16_bf16(a, b, c, 0, 0, 0);
}

#define GLDS(gsrc, ldst)                                                        \
    __builtin_amdgcn_global_load_lds(                                           \
        (const __attribute__((address_space(1))) void*)(gsrc),                  \
        (__attribute__((address_space(3))) void*)(ldst), 16, 0, 0)

// ---------- fp32 -> bf16 convert ----------
__global__ __launch_bounds__(256) void cvt_f32_bf16_kernel(
    const float* __restrict__ in, bf16u* __restrict__ out, int n) {
    union Pack { bf16u h[8]; uint4 u; };
    for (int i = (blockIdx.x * 256 + threadIdx.x) * 8; i < n; i += gridDim.x * 256 * 8) {
        const float4 a = *(const float4*)(in + i);
        const float4 b = *(const float4*)(in + i + 4);
        Pack p;
        p.h[0] = f2bf(a.x); p.h[1] = f2bf(a.y); p.h[2] = f2bf(a.z); p.h[3] = f2bf(a.w);
        p.h[4] = f2bf(b.x); p.h[5] = f2bf(b.y); p.h[6] = f2bf(b.z); p.h[7] = f2bf(b.w);
        *(uint4*)(out + i) = p.u;
    }
}

// ---------- GEMM: C = A @ Bt^T (+bias). A:[M,K] bf16, Bt:[N,K] bf16 ----------
// MODE 0: fp32 out to Cf[M,N].
// MODE 1: scatter bf16: Q (pre-scaled by QSCALE), K -> [BH][2048][64];
//         V -> TRANSPOSED [BH][64][2048].
template <int MODE>
__global__ __launch_bounds__(256) void gemm_bt_kernel(
    const bf16u* __restrict__ A, const bf16u* __restrict__ Bt,
    const float* __restrict__ bias, float* __restrict__ Cf,
    bf16u* __restrict__ Qo, bf16u* __restrict__ Ko, bf16u* __restrict__ Vto,
    int M, int N, int K) {
    __shared__ bf16u As[128 * 32];   // [row][k], linear (global_load_lds dest)
    __shared__ bf16u Bs[128 * 32];
    const int tid  = threadIdx.x;
    const int wave = tid >> 6, lane = tid & 63;
    const int wr = wave >> 1, wc = wave & 1;
    const int ri = lane & 15, hi = lane >> 4;
    const int m0 = blockIdx.x * 128, n0 = blockIdx.y * 128;

    f32x4 acc[4][4];
#pragma unroll
    for (int i = 0; i < 4; ++i)
#pragma unroll
        for (int j = 0; j < 4; ++j) acc[i][j] = (f32x4){0.f, 0.f, 0.f, 0.f};

    for (int k0 = 0; k0 < K; k0 += 32) {
        __syncthreads();
#pragma unroll
        for (int it = 0; it < 2; ++it) {
            const int chunk = it * 4 + wave;          // 0..7, wave-uniform
            const int e = chunk * 512 + lane * 8;
            const int r = e >> 5, c = e & 31;
            GLDS(A  + (size_t)(m0 + r) * K + (k0 + c), As + chunk * 512);
            GLDS(Bt + (size_t)(n0 + r) * K + (k0 + c), Bs + chunk * 512);
        }
        __syncthreads();
        s16x8 af[4], bfr[4];
#pragma unroll
        for (int i = 0; i < 4; ++i) {
            af[i]  = *(const s16x8*)(As + (wr * 64 + i * 16 + ri) * 32 + hi * 8);
            bfr[i] = *(const s16x8*)(Bs + (wc * 64 + i * 16 + ri) * 32 + hi * 8);
        }
#pragma unroll
        for (int i = 0; i < 4; ++i)
#pragma unroll
            for (int j = 0; j < 4; ++j) acc[i][j] = mfma16(af[i], bfr[j], acc[i][j]);
    }

    // epilogue: D layout row=(lane>>4)*4+r, col=lane&15
#pragma unroll
    for (int i = 0; i < 4; ++i) {
#pragma unroll
        for (int j = 0; j < 4; ++j) {
#pragma unroll
            for (int r = 0; r < 4; ++r) {
                const int row = m0 + wr * 64 + i * 16 + hi * 4 + r;
                const int col = n0 + wc * 64 + j * 16 + ri;
                const float v = acc[i][j][r] + bias[col];
                if constexpr (MODE == 0) {
                    Cf[(size_t)row * N + col] = v;
                } else {
                    const int which = col >> 10, h = (col >> 6) & 15, d = col & 63;
                    const int b = row >> 11, t = row & 2047;
                    const int bh = b * 16 + h;
                    if (which == 2) {
                        Vto[(((size_t)bh) * 64 + d) * 2048 + t] = f2bf(v);
                    } else if (which == 0) {
                        Qo[(((size_t)bh) * 2048 + t) * 64 + d] = f2bf(v * QSCALE);
                    } else {
                        Ko[(((size_t)bh) * 2048 + t) * 64 + d] = f2bf(v);
                    }
                }
            }
        }
    }
}

// ---------- flash attention (swapped QK^T, 32x32 MFMA) ----------
// Q,K: [BH][2048][64]; Vt: [BH][64][2048]; O: [B][2048][1024] bf16
// Block: 4 waves x 32 q-rows = 128 q. KV tile = 64. Grid (2048/128, BH).
// LDS rows padded to 72 elems (144B): bank-quad = (row+slot)&7 -> conflict-free.
__global__ __launch_bounds__(256) void attn_kernel(
    const bf16u* __restrict__ Q, const bf16u* __restrict__ K,
    const bf16u* __restrict__ Vt, bf16u* __restrict__ O) {
    __shared__ bf16u Ks[64 * 72];    // [k][d] pad72
    __shared__ bf16u Vs[64 * 72];    // [d][k] pad72
    const int tid = threadIdx.x, lane = tid & 63;
    const int wave = tid >> 6;
    const int ri = lane & 31, hi = lane >> 5;          // q-col / lane-half
    const int bh = blockIdx.y, b = bh >> 4, h = bh & 15;
    const int q0 = blockIdx.x * 128 + wave * 32;
    const bf16u* Qb = Q  + (size_t)bh * 2048 * 64;
    const bf16u* Kb = K  + (size_t)bh * 2048 * 64;
    const bf16u* Vb = Vt + (size_t)bh * 64 * 2048;

    // Q fragment (B-operand): lane holds row q0+ri, d = 16c + 8hi + e
    s16x8 qf[4];
#pragma unroll
    for (int c = 0; c < 4; ++c)
        qf[c] = *(const s16x8*)(Qb + (size_t)(q0 + ri) * 64 + c * 16 + hi * 8);

    f32x16 oacc[2];
#pragma unroll
    for (int r = 0; r < 16; ++r) { oacc[0][r] = 0.f; oacc[1][r] = 0.f; }
    float m = -1e30f, lsum = 0.f;

    for (int kt = 0; kt < 32; ++kt) {
        const int kv0 = kt * 64;
        // load tile to registers (issued before the barrier -> overlaps drain)
        uint4 kreg[2], vreg[2];
#pragma unroll
        for (int p = 0; p < 2; ++p) {
            const int chunkid = p * 256 + tid;       // 0..511
            const int row = chunkid >> 3, c = chunkid & 7;
            kreg[p] = *(const uint4*)(Kb + (size_t)(kv0 + row) * 64 + c * 8);
            vreg[p] = *(const uint4*)(Vb + (size_t)row * 2048 + kv0 + c * 8);
        }
        __syncthreads();  // previous tile's LDS reads complete
#pragma unroll
        for (int p = 0; p < 2; ++p) {
            const int chunkid = p * 256 + tid;
            const int row = chunkid >> 3, c = chunkid & 7;
            *(uint4*)(Ks + row * 72 + c * 8) = kreg[p];
            *(uint4*)(Vs + row * 72 + c * 8) = vreg[p];
        }
        __syncthreads();

        // S^T[k][q] = sum_d K[k][d] Q[q][d]  (2 tiles of 32k x 32q, 4 mfma each)
        f32x16 sa[2];
#pragma unroll
        for (int r = 0; r < 16; ++r) { sa[0][r] = 0.f; sa[1][r] = 0.f; }
#pragma unroll
        for (int kb2 = 0; kb2 < 2; ++kb2) {
            const int row = kb2 * 32 + ri;
#pragma unroll
            for (int c = 0; c < 4; ++c) {
                s16x8 kf = *(const s16x8*)(Ks + row * 72 + (2 * c + hi) * 8);
                sa[kb2] = mfma32(kf, qf[c], sa[kb2]);
            }
        }

        // ---- online softmax in exp2 domain (lane owns q = q0+ri) ----
        // lane holds k = 32*kb2 + (r&3) + 8*(r>>2) + 4*hi
        float pmt[16];
#pragma unroll
        for (int r = 0; r < 16; ++r) pmt[r] = fmaxf(sa[0][r], sa[1][r]);
#pragma unroll
        for (int s = 8; s > 0; s >>= 1)
#pragma unroll
            for (int r = 0; r < s; ++r) pmt[r] = fmaxf(pmt[r], pmt[r + s]);
        const float pm = fmaxf(pmt[0], __shfl_xor(pmt[0], 32));

        // defer-max (T13): only rescale when the running max grows by > 8
        if (!__all(pm <= m + 8.f)) {
            const float mn = fmaxf(m, pm);
            const float al = __builtin_amdgcn_exp2f(m - mn);
            m = mn;
            lsum *= al;
#pragma unroll
            for (int r = 0; r < 16; ++r) { oacc[0][r] *= al; oacc[1][r] *= al; }
        }

        float rs0 = 0.f, rs1 = 0.f, rs2 = 0.f, rs3 = 0.f;
#pragma unroll
        for (int kb2 = 0; kb2 < 2; ++kb2)
#pragma unroll
            for (int r = 0; r < 16; ++r) {
                const float p = __builtin_amdgcn_exp2f(sa[kb2][r] - m);
                sa[kb2][r] = p;
                if ((r & 3) == 0) rs0 += p;
                else if ((r & 3) == 1) rs1 += p;
                else if ((r & 3) == 2) rs2 += p;
                else rs3 += p;
            }
        float rs = (rs0 + rs1) + (rs2 + rs3);
        rs += __shfl_xor(rs, 32);
        lsum += rs;

        // ---- pack P^T into B-frags: pb[k4] holds k = 16*k4 + 8*hi + e ----
        // 16 cvt_pk + round-3's (verified) shfl_xor(32) half-exchange
        s16x8 pb[4];
#pragma unroll
        for (int blk = 0; blk < 2; ++blk) {
            u32 pk[4][2];
#pragma unroll
            for (int j = 0; j < 4; ++j) {
                pk[j][0] = cvtpk(sa[blk][4 * j + 0], sa[blk][4 * j + 1]);
                pk[j][1] = cvtpk(sa[blk][4 * j + 2], sa[blk][4 * j + 3]);
            }
#pragma unroll
            for (int half = 0; half < 2; ++half) {
                const int ja = 2 * half, jb = ja + 1;
                // keep own-parity quad, exchange the other with lane^32
                u32 keep0 = hi ? pk[jb][0] : pk[ja][0];
                u32 keep1 = hi ? pk[jb][1] : pk[ja][1];
                u32 send0 = hi ? pk[ja][0] : pk[jb][0];
                u32 send1 = hi ? pk[ja][1] : pk[jb][1];
                u32 recv0 = __shfl_xor(send0, 32);
                u32 recv1 = __shfl_xor(send1, 32);
                union { u32 w[4]; s16x8 v; } pu;
                pu.w[0] = hi ? recv0 : keep0;   // e0,e1
                pu.w[1] = hi ? recv1 : keep1;   // e2,e3
                pu.w[2] = hi ? keep0 : recv0;   // e4,e5
                pu.w[3] = hi ? keep1 : recv1;   // e6,e7
                pb[blk * 2 + half] = pu.v;
            }
        }

        // ---- O^T[d][q] += sum_k V^T[d][k] P^T[k][q] ----
#pragma unroll
        for (int dt = 0; dt < 2; ++dt) {
            const int row = dt * 32 + ri;
#pragma unroll
            for (int k4 = 0; k4 < 4; ++k4) {
                s16x8 vf = *(const s16x8*)(Vs + row * 72 + (2 * k4 + hi) * 8);
                oacc[dt] = mfma32(vf, pb[k4], oacc[dt]);
            }
        }
    }

    // epilogue: lane owns q-column; d = (r&3) + 8*(r>>2) + 4*hi + 32*dt
    const float inv = 1.f / lsum;
    const int t = q0 + ri;
    bf16u* Ob = O + ((size_t)b * 2048 + t) * 1024 + h * 64;
#pragma unroll
    for (int dt = 0; dt < 2; ++dt)
#pragma unroll
        for (int j = 0; j < 4; ++j) {
            const int d0 = dt * 32 + j * 8 + hi * 4;
            u32 w0 = pack2(oacc[dt][4 * j + 0] * inv, oacc[dt][4 * j + 1] * inv);
            u32 w1 = pack2(oacc[dt][4 * j + 2] * inv, oacc[dt][4 * j + 3] * inv);
            uint2 wv; wv.x = w0; wv.y = w1;
            *(uint2*)(Ob + d0) = wv;
        }
}

// ---------- launch ----------
extern "C" void kernel_launch(void* const* d_in, const int* in_sizes, int n_in,
                              void* d_out, int out_size, void* d_ws, size_t ws_size,
                              hipStream_t stream) {
    const float* x     = (const float*)d_in[0];
    const float* w_in  = (const float*)d_in[1];
    const float* b_in  = (const float*)d_in[2];
    const float* w_out = (const float*)d_in[3];
    const float* b_out = (const float*)d_in[4];
    float* out = (float*)d_out;

    char* ws = (char*)d_ws;
    bf16u* xb    = (bf16u*)(ws);                          // 8 MB  (reused as attnb)
    bf16u* wqkvb = (bf16u*)(ws + 8388608);                // 6 MB
    bf16u* woutb = (bf16u*)(ws + 14680064);               // 2 MB
    bf16u* qb    = (bf16u*)(ws + 16777216);               // 8 MB
    bf16u* kb    = (bf16u*)(ws + 25165824);               // 8 MB
    bf16u* vtb   = (bf16u*)(ws + 33554432);               // 8 MB (V stored transposed)
    bf16u* attnb = xb;  // x is dead after the QKV GEMM

    cvt_f32_bf16_kernel<<<2048, 256, 0, stream>>>(x, xb, 4096 * 1024);
    cvt_f32_bf16_kernel<<<1536, 256, 0, stream>>>(w_in, wqkvb, 3072 * 1024);
    cvt_f32_bf16_kernel<<<512, 256, 0, stream>>>(w_out, woutb, 1024 * 1024);

    gemm_bt_kernel<1><<<dim3(32, 24), 256, 0, stream>>>(
        xb, wqkvb, b_in, nullptr, qb, kb, vtb, 4096, 3072, 1024);

    attn_kernel<<<dim3(16, 32), 256, 0, stream>>>(qb, kb, vtb, attnb);

    gemm_bt_kernel<0><<<dim3(32, 8), 256, 0, stream>>>(
        attnb, woutb, b_out, out, nullptr, nullptr, nullptr, 4096, 1024, 1024);
}

// Round 6
// 151.216 us; speedup vs baseline: 1.2817x; 1.1550x over previous
//
#include <hip/hip_runtime.h>
#include <stdint.h>

// ---------- types ----------
typedef unsigned short bf16u;                                    // raw bf16 bits
typedef unsigned int u32;
typedef __attribute__((ext_vector_type(8))) short s16x8;         // MFMA A/B frag (8 bf16)
typedef __attribute__((ext_vector_type(4))) float f32x4;         // 16x16 C/D frag
typedef __attribute__((ext_vector_type(16))) float f32x16;       // 32x32 C/D frag

// Q is pre-scaled by 1/sqrt(64) * log2(e) so softmax runs in exp2 domain.
#define QSCALE 0.18033688011112042f

static __device__ __forceinline__ bf16u f2bf(float f) {
    uint32_t u = __float_as_uint(f);
    uint32_t r = (u + 0x7FFFu + ((u >> 16) & 1u)) >> 16;         // RNE
    return (bf16u)r;
}
static __device__ __forceinline__ u32 pack2(float lo, float hi) {
    return (u32)f2bf(lo) | ((u32)f2bf(hi) << 16);
}
// D.lo = bf16(S0), D.hi = bf16(S1), RNE (T12 recipe, m240)
static __device__ __forceinline__ u32 cvtpk(float lo, float hi) {
    u32 r;
    asm("v_cvt_pk_bf16_f32 %0, %1, %2" : "=v"(r) : "v"(lo), "v"(hi));
    return r;
}

static __device__ __forceinline__ f32x4 mfma16(s16x8 a, s16x8 b, f32x4 c) {
    return __builtin_amdgcn_mfma_f32_16x16x32_bf16(a, b, c, 0, 0, 0);
}
static __device__ __forceinline__ f32x16 mfma32(s16x8 a, s16x8 b, f32x16 c) {
    return __builtin_amdgcn_mfma_f32_32x32x16_bf16(a, b, c, 0, 0, 0);
}

#define GLDS(gsrc, ldst)                                                        \
    __builtin_amdgcn_global_load_lds(                                           \
        (const __attribute__((address_space(1))) void*)(gsrc),                  \
        (__attribute__((address_space(3))) void*)(ldst), 16, 0, 0)

// ---------- fp32 -> bf16 convert ----------
__global__ __launch_bounds__(256) void cvt_f32_bf16_kernel(
    const float* __restrict__ in, bf16u* __restrict__ out, int n) {
    union Pack { bf16u h[8]; uint4 u; };
    for (int i = (blockIdx.x * 256 + threadIdx.x) * 8; i < n; i += gridDim.x * 256 * 8) {
        const float4 a = *(const float4*)(in + i);
        const float4 b = *(const float4*)(in + i + 4);
        Pack p;
        p.h[0] = f2bf(a.x); p.h[1] = f2bf(a.y); p.h[2] = f2bf(a.z); p.h[3] = f2bf(a.w);
        p.h[4] = f2bf(b.x); p.h[5] = f2bf(b.y); p.h[6] = f2bf(b.z); p.h[7] = f2bf(b.w);
        *(uint4*)(out + i) = p.u;
    }
}

// ---------- GEMM: C = A @ Bt^T (+bias). A:[M,K] bf16, Bt:[N,K] bf16 ----------
// MODE 0: fp32 out to Cf[M,N].
// MODE 1: scatter bf16: Q (pre-scaled by QSCALE), K -> [BH][2048][64];
//         V -> TRANSPOSED [BH][64][2048].
template <int MODE>
__global__ __launch_bounds__(256) void gemm_bt_kernel(
    const bf16u* __restrict__ A, const bf16u* __restrict__ Bt,
    const float* __restrict__ bias, float* __restrict__ Cf,
    bf16u* __restrict__ Qo, bf16u* __restrict__ Ko, bf16u* __restrict__ Vto,
    int M, int N, int K) {
    __shared__ bf16u As[128 * 32];   // [row][k], linear (global_load_lds dest)
    __shared__ bf16u Bs[128 * 32];
    const int tid  = threadIdx.x;
    const int wave = tid >> 6, lane = tid & 63;
    const int wr = wave >> 1, wc = wave & 1;
    const int ri = lane & 15, hi = lane >> 4;
    const int m0 = blockIdx.x * 128, n0 = blockIdx.y * 128;

    f32x4 acc[4][4];
#pragma unroll
    for (int i = 0; i < 4; ++i)
#pragma unroll
        for (int j = 0; j < 4; ++j) acc[i][j] = (f32x4){0.f, 0.f, 0.f, 0.f};

    for (int k0 = 0; k0 < K; k0 += 32) {
        __syncthreads();
#pragma unroll
        for (int it = 0; it < 2; ++it) {
            const int chunk = it * 4 + wave;          // 0..7, wave-uniform
            const int e = chunk * 512 + lane * 8;
            const int r = e >> 5, c = e & 31;
            GLDS(A  + (size_t)(m0 + r) * K + (k0 + c), As + chunk * 512);
            GLDS(Bt + (size_t)(n0 + r) * K + (k0 + c), Bs + chunk * 512);
        }
        __syncthreads();
        s16x8 af[4], bfr[4];
#pragma unroll
        for (int i = 0; i < 4; ++i) {
            af[i]  = *(const s16x8*)(As + (wr * 64 + i * 16 + ri) * 32 + hi * 8);
            bfr[i] = *(const s16x8*)(Bs + (wc * 64 + i * 16 + ri) * 32 + hi * 8);
        }
#pragma unroll
        for (int i = 0; i < 4; ++i)
#pragma unroll
            for (int j = 0; j < 4; ++j) acc[i][j] = mfma16(af[i], bfr[j], acc[i][j]);
    }

    // epilogue: D layout row=(lane>>4)*4+r, col=lane&15
#pragma unroll
    for (int i = 0; i < 4; ++i) {
#pragma unroll
        for (int j = 0; j < 4; ++j) {
#pragma unroll
            for (int r = 0; r < 4; ++r) {
                const int row = m0 + wr * 64 + i * 16 + hi * 4 + r;
                const int col = n0 + wc * 64 + j * 16 + ri;
                const float v = acc[i][j][r] + bias[col];
                if constexpr (MODE == 0) {
                    Cf[(size_t)row * N + col] = v;
                } else {
                    const int which = col >> 10, h = (col >> 6) & 15, d = col & 63;
                    const int b = row >> 11, t = row & 2047;
                    const int bh = b * 16 + h;
                    if (which == 2) {
                        Vto[(((size_t)bh) * 64 + d) * 2048 + t] = f2bf(v);
                    } else if (which == 0) {
                        Qo[(((size_t)bh) * 2048 + t) * 64 + d] = f2bf(v * QSCALE);
                    } else {
                        Ko[(((size_t)bh) * 2048 + t) * 64 + d] = f2bf(v);
                    }
                }
            }
        }
    }
}

// ---------- flash attention (swapped QK^T, 32x32 MFMA, KV-split) ----------
// Q,K: [BH][2048][64]; Vt: [BH][64][2048]; O: [B][2048][1024] bf16
// Block: 8 waves (512 thr). Wave-groups {0-3}/{4-7}: same 128 q-rows,
// disjoint KV halves (tiles 0-15 / 16-31); flash-merge at the end.
// LDS rows padded to 72 elems: bank-quad = (row+slot)&7 -> conflict-free.
__global__ __launch_bounds__(512) void attn_kernel(
    const bf16u* __restrict__ Q, const bf16u* __restrict__ K,
    const bf16u* __restrict__ Vt, bf16u* __restrict__ O) {
    __shared__ uint4 smem4[4 * 64 * 72 * 2 / 16];   // 36864 B: 4 staging tiles
    bf16u* Ks0 = (bf16u*)smem4;
    bf16u* Vs0 = Ks0 + 64 * 72;
    bf16u* Ks1 = Vs0 + 64 * 72;
    bf16u* Vs1 = Ks1 + 64 * 72;
    float* mrg = (float*)smem4;                     // overlay after loop: [4][64][35]

    const int tid = threadIdx.x, lane = tid & 63;
    const int wave = tid >> 6, wg = wave & 3, half = wave >> 2;
    const int ri = lane & 31, hi = lane >> 5;          // q-col / lane-half
    const int bh = blockIdx.y, b = bh >> 4, h = bh & 15;
    const int q0 = blockIdx.x * 128 + wg * 32;
    const bf16u* Qb = Q  + (size_t)bh * 2048 * 64;
    const bf16u* Kb = K  + (size_t)bh * 2048 * 64;
    const bf16u* Vb = Vt + (size_t)bh * 64 * 2048;

    // Q fragment (B-operand): lane holds row q0+ri, d = 16c + 8hi + e
    s16x8 qf[4];
#pragma unroll
    for (int c = 0; c < 4; ++c)
        qf[c] = *(const s16x8*)(Qb + (size_t)(q0 + ri) * 64 + c * 16 + hi * 8);

    const bf16u* Ksh = half ? Ks1 : Ks0;
    const bf16u* Vsh = half ? Vs1 : Vs0;

    f32x16 oacc[2];
#pragma unroll
    for (int r = 0; r < 16; ++r) { oacc[0][r] = 0.f; oacc[1][r] = 0.f; }
    float m = -1e30f, lsum = 0.f;

    const int srow = tid >> 3, sc = tid & 7;           // 512 thr: one 16B chunk/tile
    for (int kt = 0; kt < 16; ++kt) {
        // load both halves' tiles to registers (issued before the barrier)
        const uint4 k0 = *(const uint4*)(Kb + (size_t)(kt * 64 + srow) * 64 + sc * 8);
        const uint4 k1 = *(const uint4*)(Kb + (size_t)((kt + 16) * 64 + srow) * 64 + sc * 8);
        const uint4 v0 = *(const uint4*)(Vb + (size_t)srow * 2048 + kt * 64 + sc * 8);
        const uint4 v1 = *(const uint4*)(Vb + (size_t)srow * 2048 + (kt + 16) * 64 + sc * 8);
        __syncthreads();  // previous tile's LDS reads complete
        *(uint4*)(Ks0 + srow * 72 + sc * 8) = k0;
        *(uint4*)(Ks1 + srow * 72 + sc * 8) = k1;
        *(uint4*)(Vs0 + srow * 72 + sc * 8) = v0;
        *(uint4*)(Vs1 + srow * 72 + sc * 8) = v1;
        __syncthreads();

        // S^T[k][q] = sum_d K[k][d] Q[q][d]  (2 tiles of 32k x 32q, 4 mfma each)
        f32x16 sa[2];
#pragma unroll
        for (int r = 0; r < 16; ++r) { sa[0][r] = 0.f; sa[1][r] = 0.f; }
#pragma unroll
        for (int kb2 = 0; kb2 < 2; ++kb2) {
            const int row = kb2 * 32 + ri;
#pragma unroll
            for (int c = 0; c < 4; ++c) {
                s16x8 kf = *(const s16x8*)(Ksh + row * 72 + (2 * c + hi) * 8);
                sa[kb2] = mfma32(kf, qf[c], sa[kb2]);
            }
        }

        // ---- online softmax in exp2 domain (lane owns q = q0+ri) ----
        float pmt[16];
#pragma unroll
        for (int r = 0; r < 16; ++r) pmt[r] = fmaxf(sa[0][r], sa[1][r]);
#pragma unroll
        for (int s = 8; s > 0; s >>= 1)
#pragma unroll
            for (int r = 0; r < s; ++r) pmt[r] = fmaxf(pmt[r], pmt[r + s]);
        const float pm = fmaxf(pmt[0], __shfl_xor(pmt[0], 32));

        // defer-max (T13): only rescale when the running max grows by > 8
        if (!__all(pm <= m + 8.f)) {
            const float mn = fmaxf(m, pm);
            const float al = __builtin_amdgcn_exp2f(m - mn);
            m = mn;
            lsum *= al;
#pragma unroll
            for (int r = 0; r < 16; ++r) { oacc[0][r] *= al; oacc[1][r] *= al; }
        }

        float rs0 = 0.f, rs1 = 0.f, rs2 = 0.f, rs3 = 0.f;
#pragma unroll
        for (int kb2 = 0; kb2 < 2; ++kb2)
#pragma unroll
            for (int r = 0; r < 16; ++r) {
                const float p = __builtin_amdgcn_exp2f(sa[kb2][r] - m);
                sa[kb2][r] = p;
                if ((r & 3) == 0) rs0 += p;
                else if ((r & 3) == 1) rs1 += p;
                else if ((r & 3) == 2) rs2 += p;
                else rs3 += p;
            }
        float rs = (rs0 + rs1) + (rs2 + rs3);
        rs += __shfl_xor(rs, 32);
        lsum += rs;

        // ---- pack P^T into B-frags: pb[k4] holds k = 16*k4 + 8*hi + e ----
        s16x8 pb[4];
#pragma unroll
        for (int blk = 0; blk < 2; ++blk) {
            u32 pk[4][2];
#pragma unroll
            for (int j = 0; j < 4; ++j) {
                pk[j][0] = cvtpk(sa[blk][4 * j + 0], sa[blk][4 * j + 1]);
                pk[j][1] = cvtpk(sa[blk][4 * j + 2], sa[blk][4 * j + 3]);
            }
#pragma unroll
            for (int halfq = 0; halfq < 2; ++halfq) {
                const int ja = 2 * halfq, jb = ja + 1;
                u32 keep0 = hi ? pk[jb][0] : pk[ja][0];
                u32 keep1 = hi ? pk[jb][1] : pk[ja][1];
                u32 send0 = hi ? pk[ja][0] : pk[jb][0];
                u32 send1 = hi ? pk[ja][1] : pk[jb][1];
                u32 recv0 = __shfl_xor(send0, 32);
                u32 recv1 = __shfl_xor(send1, 32);
                union { u32 w[4]; s16x8 v; } pu;
                pu.w[0] = hi ? recv0 : keep0;   // e0,e1
                pu.w[1] = hi ? recv1 : keep1;   // e2,e3
                pu.w[2] = hi ? keep0 : recv0;   // e4,e5
                pu.w[3] = hi ? keep1 : recv1;   // e6,e7
                pb[blk * 2 + halfq] = pu.v;
            }
        }

        // ---- O^T[d][q] += sum_k V^T[d][k] P^T[k][q] ----
#pragma unroll
        for (int dt = 0; dt < 2; ++dt) {
            const int row = dt * 32 + ri;
#pragma unroll
            for (int k4 = 0; k4 < 4; ++k4) {
                s16x8 vf = *(const s16x8*)(Vsh + row * 72 + (2 * k4 + hi) * 8);
                oacc[dt] = mfma32(vf, pb[k4], oacc[dt]);
            }
        }
    }

    // ---- flash merge of the two KV halves (overlay on staging LDS) ----
    __syncthreads();  // all staging reads done before overlay writes
    if (half) {
        float* p = mrg + (wg * 64 + lane) * 35;
        p[0] = m; p[1] = lsum;
#pragma unroll
        for (int r = 0; r < 16; ++r) { p[2 + r] = oacc[0][r]; p[18 + r] = oacc[1][r]; }
    }
    __syncthreads();
    if (!half) {
        const float* p = mrg + (wg * 64 + lane) * 35;
        const float m1 = p[0], l1 = p[1];
        const float mn = fmaxf(m, m1);
        const float a0 = __builtin_amdgcn_exp2f(m - mn);
        const float a1 = __builtin_amdgcn_exp2f(m1 - mn);
        const float inv = 1.f / (lsum * a0 + l1 * a1);
        const int t = q0 + ri;
        bf16u* Ob = O + ((size_t)b * 2048 + t) * 1024 + h * 64;
#pragma unroll
        for (int dt = 0; dt < 2; ++dt)
#pragma unroll
            for (int j = 0; j < 4; ++j) {
                const int d0 = dt * 32 + j * 8 + hi * 4;
                const float e0 = (oacc[dt][4 * j + 0] * a0 + p[2 + dt * 16 + 4 * j + 0] * a1) * inv;
                const float e1 = (oacc[dt][4 * j + 1] * a0 + p[2 + dt * 16 + 4 * j + 1] * a1) * inv;
                const float e2 = (oacc[dt][4 * j + 2] * a0 + p[2 + dt * 16 + 4 * j + 2] * a1) * inv;
                const float e3 = (oacc[dt][4 * j + 3] * a0 + p[2 + dt * 16 + 4 * j + 3] * a1) * inv;
                uint2 wv; wv.x = pack2(e0, e1); wv.y = pack2(e2, e3);
                *(uint2*)(Ob + d0) = wv;
            }
    }
}

// ---------- launch ----------
extern "C" void kernel_launch(void* const* d_in, const int* in_sizes, int n_in,
                              void* d_out, int out_size, void* d_ws, size_t ws_size,
                              hipStream_t stream) {
    const float* x     = (const float*)d_in[0];
    const float* w_in  = (const float*)d_in[1];
    const float* b_in  = (const float*)d_in[2];
    const float* w_out = (const float*)d_in[3];
    const float* b_out = (const float*)d_in[4];
    float* out = (float*)d_out;

    char* ws = (char*)d_ws;
    bf16u* xb    = (bf16u*)(ws);                          // 8 MB  (reused as attnb)
    bf16u* wqkvb = (bf16u*)(ws + 8388608);                // 6 MB
    bf16u* woutb = (bf16u*)(ws + 14680064);               // 2 MB
    bf16u* qb    = (bf16u*)(ws + 16777216);               // 8 MB
    bf16u* kb    = (bf16u*)(ws + 25165824);               // 8 MB
    bf16u* vtb   = (bf16u*)(ws + 33554432);               // 8 MB (V stored transposed)
    bf16u* attnb = xb;  // x is dead after the QKV GEMM

    cvt_f32_bf16_kernel<<<2048, 256, 0, stream>>>(x, xb, 4096 * 1024);
    cvt_f32_bf16_kernel<<<1536, 256, 0, stream>>>(w_in, wqkvb, 3072 * 1024);
    cvt_f32_bf16_kernel<<<512, 256, 0, stream>>>(w_out, woutb, 1024 * 1024);

    gemm_bt_kernel<1><<<dim3(32, 24), 256, 0, stream>>>(
        xb, wqkvb, b_in, nullptr, qb, kb, vtb, 4096, 3072, 1024);

    attn_kernel<<<dim3(16, 32), 512, 0, stream>>>(qb, kb, vtb, attnb);

    gemm_bt_kernel<0><<<dim3(32, 8), 256, 0, stream>>>(
        attnb, woutb, b_out, out, nullptr, nullptr, nullptr, 4096, 1024, 1024);
}